// Round 1
// baseline (297.883 us; speedup 1.0000x reference)
//
#include <hip/hip_runtime.h>
#include <math.h>

// Problem constants (from reference setup_inputs)
#define NB 4
#define NC 4
#define NH 4
#define NN 1024
#define NF 64
#define NCOMBO (NB*NC*NH)   // 64
#define LEAK 0.2f

// ---------------------------------------------------------------------------
// k1: h_prime[g,n,o] = sum_f h[b,c,n,f] * w[c,h,f,o]
//     asrc[g,n] = sum_o tanh(hp) * a_src[c,h,o]   (adst likewise)
// One block = one combo g x 64 rows. w (16KB) staged in LDS.
// ---------------------------------------------------------------------------
__global__ __launch_bounds__(256) void k1_hprime(
    const float* __restrict__ h, const float* __restrict__ w,
    const float* __restrict__ a_src, const float* __restrict__ a_dst,
    float* __restrict__ hp, float* __restrict__ asrc, float* __restrict__ adst)
{
    __shared__ float w_lds[NF*NF];
    __shared__ float as_lds[NF], ad_lds[NF];
    const int g    = blockIdx.x >> 4;
    const int tile = blockIdx.x & 15;
    const int b  = g >> 4;
    const int c  = (g >> 2) & 3;
    const int hh = g & 3;
    const int t  = threadIdx.x;

    const float4* wsrc = (const float4*)(w + (c*NH + hh)*NF*NF);
    #pragma unroll
    for (int i = 0; i < 4; ++i)
        ((float4*)w_lds)[t + i*256] = wsrc[t + i*256];
    if (t < NF) {
        as_lds[t] = a_src[(c*NH + hh)*NF + t];
        ad_lds[t] = a_dst[(c*NH + hh)*NF + t];
    }
    __syncthreads();

    const int wave = t >> 6, lane = t & 63;
    for (int it = 0; it < 16; ++it) {
        const int n = tile*64 + wave*16 + it;
        const float hv = h[((b*NC + c)*NN + n)*NF + lane];
        float acc = 0.f;
        #pragma unroll
        for (int f = 0; f < NF; ++f)
            acc = fmaf(__shfl(hv, f), w_lds[f*NF + lane], acc);
        hp[(g*NN + n)*NF + lane] = acc;
        const float tt = tanhf(acc);
        float ps = tt * as_lds[lane];
        float pd = tt * ad_lds[lane];
        #pragma unroll
        for (int off = 32; off > 0; off >>= 1) {
            ps += __shfl_down(ps, off);
            pd += __shfl_down(pd, off);
        }
        if (lane == 0) { asrc[g*NN + n] = ps; adst[g*NN + n] = pd; }
    }
}

// ---------------------------------------------------------------------------
// k2: bits[b][i][j/64] — bit set where (adj[b,i,j] != 0) || (j == i)
// ---------------------------------------------------------------------------
__global__ __launch_bounds__(256) void k2_bits(
    const float* __restrict__ adj, unsigned long long* __restrict__ bits)
{
    const int idx = blockIdx.x*256 + threadIdx.x;   // over B*N*N = 4M
    const int j  = idx & (NN-1);
    const int i  = (idx >> 10) & (NN-1);
    const int bb = idx >> 20;
    const float av = adj[idx];
    const bool pred = (av != 0.f) || (j == i);
    const unsigned long long m = __ballot(pred);
    if ((j & 63) == 0) bits[(bb*NN + i)*(NN/64) + (j >> 6)] = m;
}

// ---------------------------------------------------------------------------
// k3: per block: one combo g, 64 i-rows. Masked-softmax over j of
// lrelu(src_i+dst_j), then out[i,:] = sum_j p_ij * hp[j,:] / l_i.
// j tiled by 64: hp tile + p tile staged in LDS; float4 accumulate.
// ---------------------------------------------------------------------------
__global__ __launch_bounds__(256) void k3_attn(
    const float* __restrict__ hp, const float* __restrict__ asrc,
    const float* __restrict__ adst, const unsigned long long* __restrict__ bits,
    float* __restrict__ out)
{
    __shared__ float dst_lds[NN];                 // 4KB
    __shared__ float src_lds[64];
    __shared__ float m_lds[64];
    __shared__ float l_lds[64];
    __shared__ float red_lds[256];
    __shared__ unsigned long long bits_lds[64*16]; // 8KB
    __shared__ float hp_lds[64*64];                // 16KB
    __shared__ float p_lds[64*68];                 // padded stride 68 (bank decorrelation)

    const int g  = blockIdx.x >> 4;
    const int ti = blockIdx.x & 15;
    const int b  = g >> 4;
    const int t  = threadIdx.x;
    const int i0 = ti*64;

    ((float4*)dst_lds)[t] = ((const float4*)(adst + g*NN))[t];
    if (t < 64) src_lds[t] = asrc[g*NN + i0 + t];
    #pragma unroll
    for (int i = 0; i < 4; ++i)
        bits_lds[t + i*256] = bits[(b*NN + i0)*16 + t + i*256];
    __syncthreads();

    // masked max of dst per row -> m_i = lrelu(src_i + maxdst_i)
    {
        const int r = t >> 2, q = t & 3;
        float mx = -1e30f;
        #pragma unroll
        for (int jw = 0; jw < 4; ++jw) {
            const unsigned long long wb = bits_lds[r*16 + q*4 + jw];
            const float* dp = dst_lds + (q*4 + jw)*64;
            for (int k2 = 0; k2 < 64; ++k2) {
                const float v = dp[k2];
                mx = ((wb >> k2) & 1ull) ? fmaxf(mx, v) : mx;
            }
        }
        red_lds[t] = mx;
    }
    __syncthreads();
    if (t < 64) {
        const float mx = fmaxf(fmaxf(red_lds[t*4], red_lds[t*4+1]),
                               fmaxf(red_lds[t*4+2], red_lds[t*4+3]));
        const float s = src_lds[t] + mx;
        m_lds[t] = (s >= 0.f) ? s : LEAK*s;
    }

    float acc[4][4];
    #pragma unroll
    for (int k = 0; k < 4; ++k) {
        acc[k][0] = 0.f; acc[k][1] = 0.f; acc[k][2] = 0.f; acc[k][3] = 0.f;
    }
    float psum = 0.f;
    const int pr = t >> 2, pq = t & 3;     // p-compute mapping: row pr, j-quarter pq
    const int ocol = t & 15, rq = t >> 4;  // accumulate mapping: o = ocol*4, rows rq*4+k

    for (int tj = 0; tj < 16; ++tj) {
        __syncthreads();
        // stage hp tile (64 j-rows x 64 o)
        {
            const float4* s = (const float4*)(hp + (g*NN + tj*64)*NF);
            #pragma unroll
            for (int i = 0; i < 4; ++i)
                ((float4*)hp_lds)[t + i*256] = s[t + i*256];
        }
        // compute p tile
        {
            const float m  = m_lds[pr];
            const float sv = src_lds[pr];
            const unsigned long long wb = bits_lds[pr*16 + tj];
            #pragma unroll
            for (int k = 0; k < 16; ++k) {
                const int jl = pq*16 + k;
                float s = sv + dst_lds[tj*64 + jl];
                s = (s >= 0.f) ? s : LEAK*s;
                const float p = ((wb >> jl) & 1ull) ? __expf(s - m) : 0.f;
                p_lds[pr*68 + jl] = p;
                psum += p;
            }
        }
        __syncthreads();
        // accumulate: out[r][o..o+3] += p[r][j] * hp[j][o..o+3]
        #pragma unroll 4
        for (int jj = 0; jj < 64; jj += 4) {
            const float4 hv0 = *(const float4*)&hp_lds[(jj+0)*64 + ocol*4];
            const float4 hv1 = *(const float4*)&hp_lds[(jj+1)*64 + ocol*4];
            const float4 hv2 = *(const float4*)&hp_lds[(jj+2)*64 + ocol*4];
            const float4 hv3 = *(const float4*)&hp_lds[(jj+3)*64 + ocol*4];
            #pragma unroll
            for (int k = 0; k < 4; ++k) {
                const float4 pv = *(const float4*)&p_lds[(rq*4 + k)*68 + jj];
                acc[k][0] = fmaf(pv.x, hv0.x, acc[k][0]);
                acc[k][0] = fmaf(pv.y, hv1.x, acc[k][0]);
                acc[k][0] = fmaf(pv.z, hv2.x, acc[k][0]);
                acc[k][0] = fmaf(pv.w, hv3.x, acc[k][0]);
                acc[k][1] = fmaf(pv.x, hv0.y, acc[k][1]);
                acc[k][1] = fmaf(pv.y, hv1.y, acc[k][1]);
                acc[k][1] = fmaf(pv.z, hv2.y, acc[k][1]);
                acc[k][1] = fmaf(pv.w, hv3.y, acc[k][1]);
                acc[k][2] = fmaf(pv.x, hv0.z, acc[k][2]);
                acc[k][2] = fmaf(pv.y, hv1.z, acc[k][2]);
                acc[k][2] = fmaf(pv.z, hv2.z, acc[k][2]);
                acc[k][2] = fmaf(pv.w, hv3.z, acc[k][2]);
                acc[k][3] = fmaf(pv.x, hv0.w, acc[k][3]);
                acc[k][3] = fmaf(pv.y, hv1.w, acc[k][3]);
                acc[k][3] = fmaf(pv.z, hv2.w, acc[k][3]);
                acc[k][3] = fmaf(pv.w, hv3.w, acc[k][3]);
            }
        }
    }
    __syncthreads();
    red_lds[t] = psum;
    __syncthreads();
    if (t < 64)
        l_lds[t] = red_lds[t*4] + red_lds[t*4+1] + red_lds[t*4+2] + red_lds[t*4+3];
    __syncthreads();
    #pragma unroll
    for (int k = 0; k < 4; ++k) {
        const int r = rq*4 + k;
        const float inv = 1.f / l_lds[r];
        float4 o4;
        o4.x = acc[k][0]*inv; o4.y = acc[k][1]*inv;
        o4.z = acc[k][2]*inv; o4.w = acc[k][3]*inv;
        *(float4*)&out[(g*NN + i0 + r)*NF + ocol*4] = o4;
    }
}

// ---------------------------------------------------------------------------
extern "C" void kernel_launch(void* const* d_in, const int* in_sizes, int n_in,
                              void* d_out, int out_size, void* d_ws, size_t ws_size,
                              hipStream_t stream)
{
    const float* h     = (const float*)d_in[0];
    const float* adj   = (const float*)d_in[1];
    const float* w     = (const float*)d_in[2];
    const float* a_src = (const float*)d_in[3];
    const float* a_dst = (const float*)d_in[4];
    float* out = (float*)d_out;

    char* ws = (char*)d_ws;
    // ws layout: hp [64][1024][64] f32 (67,108,864 B) | asrc (262,144 B) |
    //            adst (262,144 B) | bits u64 [4][1024][16] (524,288 B)
    float* hp   = (float*)ws;
    float* asrc = (float*)(ws + 67108864);
    float* adst = (float*)(ws + 67108864 + 262144);
    unsigned long long* bits = (unsigned long long*)(ws + 67108864 + 524288);

    k1_hprime<<<dim3(NCOMBO*16), dim3(256), 0, stream>>>(h, w, a_src, a_dst, hp, asrc, adst);
    k2_bits  <<<dim3(NB*NN*NN/256), dim3(256), 0, stream>>>(adj, bits);
    k3_attn  <<<dim3(NCOMBO*16), dim3(256), 0, stream>>>(hp, asrc, adst, bits, out);
}

// Round 2
// 170.019 us; speedup vs baseline: 1.7521x; 1.7521x over previous
//
#include <hip/hip_runtime.h>
#include <math.h>

// Problem constants
#define NB 4
#define NC 4
#define NH 4
#define NN 1024
#define NF 64
#define NCOMBO 64
#define LEAK 0.2f

typedef __attribute__((ext_vector_type(8)))  short  short8;
typedef __attribute__((ext_vector_type(16))) float  float16;

// round-to-nearest-even float -> bf16 bits (p,hp are never NaN)
static __device__ __forceinline__ unsigned short f2bf_rne(float x) {
    union { float f; unsigned u; } v; v.f = x;
    unsigned r = v.u + 0x7fffu + ((v.u >> 16) & 1u);
    return (unsigned short)(r >> 16);
}

// ---------------------------------------------------------------------------
// k1: hp = h @ w per combo (fp32 shfl-GEMM), writes:
//   hpt[g][o][n] bf16 (TRANSPOSED, for k3's MFMA B-fragments)
//   asrc[g][n], adst[g][n] fp32 (attention score vectors)
// ---------------------------------------------------------------------------
__global__ __launch_bounds__(256) void k1_hprime(
    const float* __restrict__ h, const float* __restrict__ w,
    const float* __restrict__ a_src, const float* __restrict__ a_dst,
    unsigned short* __restrict__ hpt, float* __restrict__ asrc,
    float* __restrict__ adst)
{
    __shared__ float w_lds[NF*NF];     // 16KB
    __shared__ float hp_s[64*65];      // 16.6KB, stride 65 breaks transpose conflicts
    __shared__ float as_lds[NF], ad_lds[NF];
    const int g    = blockIdx.x >> 4;
    const int tile = blockIdx.x & 15;
    const int b = g >> 4, c = (g >> 2) & 3, hh = g & 3;
    const int t = threadIdx.x;

    const float4* wsrc = (const float4*)(w + (c*NH + hh)*NF*NF);
    #pragma unroll
    for (int i = 0; i < 4; ++i)
        ((float4*)w_lds)[t + i*256] = wsrc[t + i*256];
    if (t < NF) {
        as_lds[t] = a_src[(c*NH + hh)*NF + t];
        ad_lds[t] = a_dst[(c*NH + hh)*NF + t];
    }
    __syncthreads();

    const int wave = t >> 6, lane = t & 63;
    for (int it = 0; it < 16; ++it) {
        const int nl = wave*16 + it;
        const int n  = tile*64 + nl;
        const float hv = h[((b*NC + c)*NN + n)*NF + lane];
        float acc = 0.f;
        #pragma unroll
        for (int f = 0; f < NF; ++f)
            acc = fmaf(__shfl(hv, f), w_lds[f*NF + lane], acc);
        hp_s[nl*65 + lane] = acc;
        const float tt = tanhf(acc);
        float ps = tt * as_lds[lane];
        float pd = tt * ad_lds[lane];
        #pragma unroll
        for (int off = 32; off > 0; off >>= 1) {
            ps += __shfl_down(ps, off);
            pd += __shfl_down(pd, off);
        }
        if (lane == 0) { asrc[g*NN + n] = ps; adst[g*NN + n] = pd; }
    }
    __syncthreads();
    // transposed bf16 write: hpt[(g*64+o)*NN + n]
    const int o = t >> 2;
    #pragma unroll
    for (int cc2 = 0; cc2 < 2; ++cc2) {
        const int cc = (t & 3) + cc2*4;
        unsigned pk[4];
        #pragma unroll
        for (int kk = 0; kk < 4; ++kk) {
            const unsigned short lo = f2bf_rne(hp_s[(cc*8 + kk*2    )*65 + o]);
            const unsigned short hi = f2bf_rne(hp_s[(cc*8 + kk*2 + 1)*65 + o]);
            pk[kk] = (unsigned)lo | ((unsigned)hi << 16);
        }
        *(uint4*)&hpt[((size_t)g*64 + o)*NN + tile*64 + cc*8] =
            make_uint4(pk[0], pk[1], pk[2], pk[3]);
    }
}

// ---------------------------------------------------------------------------
// k2: bits[b][i][j/64] — bit set where (adj[b,i,j] != 0) || (j == i)
// ---------------------------------------------------------------------------
__global__ __launch_bounds__(256) void k2_bits(
    const float* __restrict__ adj, unsigned long long* __restrict__ bits)
{
    const int idx = blockIdx.x*256 + threadIdx.x;   // over B*N*N = 4M
    const int j  = idx & (NN-1);
    const int i  = (idx >> 10) & (NN-1);
    const int bb = idx >> 20;
    const float av = adj[idx];
    const bool pred = (av != 0.f) || (j == i);
    const unsigned long long m = __ballot(pred);
    if ((j & 63) == 0) bits[((size_t)bb*NN + i)*(NN/64) + (j >> 6)] = m;
}

// ---------------------------------------------------------------------------
// k3: block = one combo g x 128 i-rows. wave w owns rows w*32..w*32+31,
// full o=0..63 via two 32x32x16 bf16 MFMAs per K=16 step. P-fragments are
// generated in registers via factored exp:
//   p = bit * ( s>=0 ? exp(src-m)*exp(dst) : exp(.2src-m)*exp(.2dst) )
// with m = lrelu(src_i + max_j dst_j)  (upper bound of the masked row max,
// valid since lrelu is monotone; diag always unmasked so no underflow risk).
// ---------------------------------------------------------------------------
__global__ __launch_bounds__(256) void k3_attn(
    const unsigned short* __restrict__ hpt, const float* __restrict__ asrc,
    const float* __restrict__ adst, const unsigned long long* __restrict__ bits,
    float* __restrict__ out)
{
    __shared__ float dst_lds[NN];                    // 4KB
    __shared__ float edP[NN], edN[NN];               // 8KB
    __shared__ float src_lds[128];
    __shared__ float l_lds[128];
    __shared__ float red_lds[64];
    __shared__ unsigned long long bits_lds[128*17];  // 17.4KB, stride 17
    __shared__ unsigned short tile_lds[64*72];       // 9.2KB, stride 72 bf16

    const int g  = blockIdx.x & 63;    // same-g blocks land on one XCD (L2 reuse)
    const int it = blockIdx.x >> 6;
    const int b  = g >> 4;
    const int t  = threadIdx.x;
    const int i0 = it*128;
    const int w = t >> 6, lane = t & 63;
    const int l31 = lane & 31, half = lane >> 5;

    ((float4*)dst_lds)[t] = ((const float4*)(adst + (size_t)g*NN))[t];
    if (t < 128) src_lds[t] = asrc[(size_t)g*NN + i0 + t];
    {
        const unsigned long long* bsrc = bits + ((size_t)b*NN + i0)*16;
        #pragma unroll
        for (int q = 0; q < 8; ++q) {
            const int idx = q*256 + t;
            bits_lds[(idx >> 4)*17 + (idx & 15)] = bsrc[idx];
        }
    }
    __syncthreads();

    // factored exp tables + global (unmasked) max of dst
    #pragma unroll
    for (int q = 0; q < 4; ++q) {
        const float d = dst_lds[q*256 + t];
        edP[q*256 + t] = __expf(d);
        edN[q*256 + t] = __expf(LEAK*d);
    }
    float mx = fmaxf(fmaxf(dst_lds[t], dst_lds[t+256]),
                     fmaxf(dst_lds[t+512], dst_lds[t+768]));
    #pragma unroll
    for (int off = 32; off > 0; off >>= 1) mx = fmaxf(mx, __shfl_down(mx, off));
    if (lane == 0) red_lds[w] = mx;
    __syncthreads();
    const float maxdst = fmaxf(fmaxf(red_lds[0], red_lds[1]),
                               fmaxf(red_lds[2], red_lds[3]));

    const int   myrow = w*32 + l31;            // local row 0..127
    const float sv  = src_lds[myrow];
    const float s0  = sv + maxdst;
    const float mi  = fmaxf(s0, LEAK*s0);      // lrelu(s0), >= true masked row max
    const float esP = __expf(sv - mi);
    const float esN = __expf(LEAK*sv - mi);
    const float thr = -sv;                     // dst >= thr  <=>  s >= 0

    float16 acc0, acc1;
    #pragma unroll
    for (int i = 0; i < 16; ++i) { acc0[i] = 0.f; acc1[i] = 0.f; }
    float psum = 0.f;

    for (int jt = 0; jt < 16; ++jt) {
        __syncthreads();
        {   // stage hp_t tile [o 0..63][j 0..63] bf16, row stride 72
            const int o = t >> 2;
            const uint4* src = (const uint4*)(hpt + ((size_t)g*64 + o)*NN + jt*64);
            const uint4 v0 = src[t & 3];
            const uint4 v1 = src[(t & 3) + 4];
            *(uint4*)&tile_lds[o*72 + (t & 3)*8]      = v0;
            *(uint4*)&tile_lds[o*72 + (t & 3)*8 + 32] = v1;
        }
        const unsigned long long wb = bits_lds[myrow*17 + jt];
        __syncthreads();

        #pragma unroll
        for (int ks = 0; ks < 4; ++ks) {
            const int jb = jt*64 + ks*16 + half*8;
            const float4 d0 = *(const float4*)&dst_lds[jb];
            const float4 d1 = *(const float4*)&dst_lds[jb + 4];
            const float4 p0 = *(const float4*)&edP[jb];
            const float4 p1 = *(const float4*)&edP[jb + 4];
            const float4 n0 = *(const float4*)&edN[jb];
            const float4 n1 = *(const float4*)&edN[jb + 4];
            const unsigned bb = (unsigned)(wb >> (ks*16 + half*8)) & 0xffu;

            union { short8 v; unsigned short u[8]; } af;
            float p;
            p = (d0.x >= thr) ? p0.x*esP : n0.x*esN; p = (bb & 1u)   ? p : 0.f; psum += p; af.u[0] = f2bf_rne(p);
            p = (d0.y >= thr) ? p0.y*esP : n0.y*esN; p = (bb & 2u)   ? p : 0.f; psum += p; af.u[1] = f2bf_rne(p);
            p = (d0.z >= thr) ? p0.z*esP : n0.z*esN; p = (bb & 4u)   ? p : 0.f; psum += p; af.u[2] = f2bf_rne(p);
            p = (d0.w >= thr) ? p0.w*esP : n0.w*esN; p = (bb & 8u)   ? p : 0.f; psum += p; af.u[3] = f2bf_rne(p);
            p = (d1.x >= thr) ? p1.x*esP : n1.x*esN; p = (bb & 16u)  ? p : 0.f; psum += p; af.u[4] = f2bf_rne(p);
            p = (d1.y >= thr) ? p1.y*esP : n1.y*esN; p = (bb & 32u)  ? p : 0.f; psum += p; af.u[5] = f2bf_rne(p);
            p = (d1.z >= thr) ? p1.z*esP : n1.z*esN; p = (bb & 64u)  ? p : 0.f; psum += p; af.u[6] = f2bf_rne(p);
            p = (d1.w >= thr) ? p1.w*esP : n1.w*esN; p = (bb & 128u) ? p : 0.f; psum += p; af.u[7] = f2bf_rne(p);

            const short8 b0 = *(const short8*)&tile_lds[(l31     )*72 + ks*16 + half*8];
            const short8 b1 = *(const short8*)&tile_lds[(l31 + 32)*72 + ks*16 + half*8];
            acc0 = __builtin_amdgcn_mfma_f32_32x32x16_bf16(af.v, b0, acc0, 0, 0, 0);
            acc1 = __builtin_amdgcn_mfma_f32_32x32x16_bf16(af.v, b1, acc1, 0, 0, 0);
        }
    }

    // row sums: halves cover j%16 in [0,8) and [8,16) -> combine across half
    psum += __shfl_xor(psum, 32);
    if (lane < 32) l_lds[w*32 + lane] = psum;
    __syncthreads();

    #pragma unroll
    for (int reg = 0; reg < 16; ++reg) {
        const int r = (reg & 3) + 8*(reg >> 2) + 4*half;   // local row 0..31
        const float inv = 1.f / l_lds[w*32 + r];
        const size_t base = ((size_t)g*NN + i0 + w*32 + r)*NF;
        out[base + l31]      = acc0[reg] * inv;
        out[base + l31 + 32] = acc1[reg] * inv;
    }
}

// ---------------------------------------------------------------------------
extern "C" void kernel_launch(void* const* d_in, const int* in_sizes, int n_in,
                              void* d_out, int out_size, void* d_ws, size_t ws_size,
                              hipStream_t stream)
{
    const float* h     = (const float*)d_in[0];
    const float* adj   = (const float*)d_in[1];
    const float* w     = (const float*)d_in[2];
    const float* a_src = (const float*)d_in[3];
    const float* a_dst = (const float*)d_in[4];
    float* out = (float*)d_out;

    char* ws = (char*)d_ws;
    // ws: hpt bf16 [64][64][1024] (8,388,608 B) | asrc (262,144) | adst (262,144)
    //     | bits u64 [4][1024][16] (524,288)
    unsigned short* hpt  = (unsigned short*)ws;
    float* asrc          = (float*)(ws + 8388608);
    float* adst          = (float*)(ws + 8388608 + 262144);
    unsigned long long* bits = (unsigned long long*)(ws + 8388608 + 524288);

    k1_hprime<<<dim3(NCOMBO*16), dim3(256), 0, stream>>>(h, w, a_src, a_dst, hpt, asrc, adst);
    k2_bits  <<<dim3(NB*NN*NN/256), dim3(256), 0, stream>>>(adj, bits);
    k3_attn  <<<dim3(512), dim3(256), 0, stream>>>(hpt, asrc, adst, bits, out);
}

// Round 3
// 140.182 us; speedup vs baseline: 2.1250x; 1.2128x over previous
//
#include <hip/hip_runtime.h>
#include <math.h>

// Problem constants
#define NB 4
#define NC 4
#define NH 4
#define NN 1024
#define NF 64
#define NCOMBO 64
#define LEAK 0.2f

typedef __attribute__((ext_vector_type(8)))  short  short8;
typedef __attribute__((ext_vector_type(16))) float  float16;

// round-to-nearest-even float -> bf16 bits (inputs never NaN)
static __device__ __forceinline__ unsigned short f2bf_rne(float x) {
    union { float f; unsigned u; } v; v.f = x;
    unsigned r = v.u + 0x7fffu + ((v.u >> 16) & 1u);
    return (unsigned short)(r >> 16);
}

// tanh via hardware exp+rcp: 1 - 2/(1+e^{2x}); err ~1e-6, saturates correctly
static __device__ __forceinline__ float fast_tanh(float x) {
    const float e = __expf(2.f * x);
    return 1.f - 2.f * __builtin_amdgcn_rcpf(1.f + e);
}

// ---------------------------------------------------------------------------
// k1: hp = h @ w per combo. LDS-tiled fp32 GEMM, 4x4 acc per thread.
// Writes hpt[g][o][n] bf16 (transposed) + asrc/adst fp32 score vectors.
// ---------------------------------------------------------------------------
__global__ __launch_bounds__(256) void k1_hprime(
    const float* __restrict__ h, const float* __restrict__ w,
    const float* __restrict__ a_src, const float* __restrict__ a_dst,
    unsigned short* __restrict__ hpt, float* __restrict__ asrc,
    float* __restrict__ adst)
{
    __shared__ __align__(16) char ovr[64*65*4];   // hT[f][r] stride 65; later redS/redD
    __shared__ float w_s[NF*NF];                  // w_s[f][o] 16KB
    __shared__ float as_lds[NF], ad_lds[NF];
    float* hT = (float*)ovr;

    const int g    = blockIdx.x >> 4;
    const int tile = blockIdx.x & 15;
    const int b = g >> 4, c = (g >> 2) & 3, hh = g & 3;
    const int t = threadIdx.x;
    const int tr = t >> 4, tc = t & 15;

    // stage w (64x64 f32) and score vectors
    const float4* wsrc = (const float4*)(w + ((size_t)(c*NH + hh))*NF*NF);
    #pragma unroll
    for (int i = 0; i < 4; ++i)
        ((float4*)w_s)[t + i*256] = wsrc[t + i*256];
    if (t < NF) {
        as_lds[t] = a_src[(c*NH + hh)*NF + t];
        ad_lds[t] = a_dst[(c*NH + hh)*NF + t];
    }
    // stage h tile transposed: hT[f][r], stride 65
    const float* hsrc = h + (((size_t)(b*NC + c))*NN + tile*64)*NF;
    #pragma unroll
    for (int i = 0; i < 4; ++i) {
        const int r = (t >> 4) + i*16, f4 = (t & 15)*4;
        const float4 v = *(const float4*)&hsrc[r*NF + f4];
        hT[(f4+0)*65 + r] = v.x; hT[(f4+1)*65 + r] = v.y;
        hT[(f4+2)*65 + r] = v.z; hT[(f4+3)*65 + r] = v.w;
    }
    __syncthreads();

    float acc[4][4] = {{0.f}};
    #pragma unroll 8
    for (int f = 0; f < 64; ++f) {
        const float4 hv = *(const float4*)&hT[f*65 + tr*4];
        const float4 wv = *(const float4*)&w_s[f*64 + tc*4];
        acc[0][0] = fmaf(hv.x, wv.x, acc[0][0]);
        acc[0][1] = fmaf(hv.x, wv.y, acc[0][1]);
        acc[0][2] = fmaf(hv.x, wv.z, acc[0][2]);
        acc[0][3] = fmaf(hv.x, wv.w, acc[0][3]);
        acc[1][0] = fmaf(hv.y, wv.x, acc[1][0]);
        acc[1][1] = fmaf(hv.y, wv.y, acc[1][1]);
        acc[1][2] = fmaf(hv.y, wv.z, acc[1][2]);
        acc[1][3] = fmaf(hv.y, wv.w, acc[1][3]);
        acc[2][0] = fmaf(hv.z, wv.x, acc[2][0]);
        acc[2][1] = fmaf(hv.z, wv.y, acc[2][1]);
        acc[2][2] = fmaf(hv.z, wv.z, acc[2][2]);
        acc[2][3] = fmaf(hv.z, wv.w, acc[2][3]);
        acc[3][0] = fmaf(hv.w, wv.x, acc[3][0]);
        acc[3][1] = fmaf(hv.w, wv.y, acc[3][1]);
        acc[3][2] = fmaf(hv.w, wv.z, acc[3][2]);
        acc[3][3] = fmaf(hv.w, wv.w, acc[3][3]);
    }

    // score partials: ps[r] = sum_c tanh(hp)*as[o], pd likewise
    float ps[4] = {0.f,0.f,0.f,0.f}, pd[4] = {0.f,0.f,0.f,0.f};
    #pragma unroll
    for (int r = 0; r < 4; ++r)
        #pragma unroll
        for (int cc = 0; cc < 4; ++cc) {
            const float tt = fast_tanh(acc[r][cc]);
            ps[r] = fmaf(tt, as_lds[tc*4+cc], ps[r]);
            pd[r] = fmaf(tt, ad_lds[tc*4+cc], pd[r]);
        }
    __syncthreads();                     // hT no longer needed -> overlay
    float* redS = (float*)ovr;           // [64][16]
    float* redD = redS + 1024;
    #pragma unroll
    for (int r = 0; r < 4; ++r) {
        redS[(tr*4+r)*16 + tc] = ps[r];
        redD[(tr*4+r)*16 + tc] = pd[r];
    }
    __syncthreads();
    if (t < 64) {
        float4 s0 = *(const float4*)&redS[t*16],     s1 = *(const float4*)&redS[t*16+4];
        float4 s2 = *(const float4*)&redS[t*16+8],   s3 = *(const float4*)&redS[t*16+12];
        asrc[(size_t)g*NN + tile*64 + t] =
            (s0.x+s0.y+s0.z+s0.w) + (s1.x+s1.y+s1.z+s1.w) +
            (s2.x+s2.y+s2.z+s2.w) + (s3.x+s3.y+s3.z+s3.w);
        float4 d0 = *(const float4*)&redD[t*16],     d1 = *(const float4*)&redD[t*16+4];
        float4 d2 = *(const float4*)&redD[t*16+8],   d3 = *(const float4*)&redD[t*16+12];
        adst[(size_t)g*NN + tile*64 + t] =
            (d0.x+d0.y+d0.z+d0.w) + (d1.x+d1.y+d1.z+d1.w) +
            (d2.x+d2.y+d2.z+d2.w) + (d3.x+d3.y+d3.z+d3.w);
    }
    // transposed bf16 hp write: hpt[(g*64+o)][tile*64 + tr*4 .. +3]
    #pragma unroll
    for (int cc = 0; cc < 4; ++cc) {
        const int o = tc*4 + cc;
        ushort4 pk;
        pk.x = f2bf_rne(acc[0][cc]); pk.y = f2bf_rne(acc[1][cc]);
        pk.z = f2bf_rne(acc[2][cc]); pk.w = f2bf_rne(acc[3][cc]);
        *(ushort4*)&hpt[((size_t)g*64 + o)*NN + tile*64 + tr*4] = pk;
    }
}

// ---------------------------------------------------------------------------
// k2: bits[b][i][j/64] — bit set where (adj[b,i,j] != 0) || (j == i)
// ---------------------------------------------------------------------------
__global__ __launch_bounds__(256) void k2_bits(
    const float* __restrict__ adj, unsigned long long* __restrict__ bits)
{
    const int idx = blockIdx.x*256 + threadIdx.x;   // over B*N*N = 4M
    const int j  = idx & (NN-1);
    const int i  = (idx >> 10) & (NN-1);
    const int bb = idx >> 20;
    const float av = adj[idx];
    const bool pred = (av != 0.f) || (j == i);
    const unsigned long long m = __ballot(pred);
    if ((j & 63) == 0) bits[((size_t)bb*NN + i)*(NN/64) + (j >> 6)] = m;
}

// ---------------------------------------------------------------------------
// k3: block = one combo g x 64 i-rows, 4 waves. Wave w: rowgroup rg=w>>1
// (rows rg*32..+31), jt-half jh=w&1 (jt in [jh*8, jh*8+8)). Pairs combine
// partial accumulators + row sums through LDS at the end.
// P generated in registers: p = bit ? exp(lrelu(src+dst) - m) : 0,
// m = lrelu(src_i + max_j dst_j) (valid upper bound; diag always unmasked).
// Mask bits live in 8 u64 registers per lane.
// ---------------------------------------------------------------------------
__global__ __launch_bounds__(256, 4) void k3_attn(
    const unsigned short* __restrict__ hpt, const float* __restrict__ asrc,
    const float* __restrict__ adst, const unsigned long long* __restrict__ bits,
    float* __restrict__ out)
{
    __shared__ float dst_lds[NN];                 // 4KB
    __shared__ float src_lds[64];
    __shared__ float ps_buf[64];
    __shared__ float red_lds[4];
    // overlay: tile[2][64*72] bf16 (18432B) during loop; comb[2][64*34] f32 after
    __shared__ __align__(16) char ovraw[2*64*72*2];
    unsigned short* tile = (unsigned short*)ovraw;
    float* comb = (float*)ovraw;

    const int g  = blockIdx.x & 63;    // same-g blocks -> same XCD stride (L2 reuse)
    const int it = blockIdx.x >> 6;    // 0..15
    const int b  = g >> 4;
    const int t  = threadIdx.x;
    const int i0 = it*64;
    const int w = t >> 6, lane = t & 63;
    const int l31 = lane & 31, half = lane >> 5;
    const int rg = w >> 1, jh = w & 1;
    const int myrow = rg*32 + l31;

    ((float4*)dst_lds)[t] = ((const float4*)(adst + (size_t)g*NN))[t];
    if (t < 64) src_lds[t] = asrc[(size_t)g*NN + i0 + t];

    // mask bits for this lane's row + jt half -> 8 u64 registers
    unsigned long long brg[8];
    {
        const ulonglong2* bp = (const ulonglong2*)
            (bits + (((size_t)b*NN) + i0 + myrow)*16 + jh*8);
        #pragma unroll
        for (int q = 0; q < 4; ++q) {
            const ulonglong2 v = bp[q];
            brg[q*2] = v.x; brg[q*2+1] = v.y;
        }
    }
    __syncthreads();

    // global (unmasked) max of dst — valid softmax shift upper bound
    float mx = fmaxf(fmaxf(dst_lds[t], dst_lds[t+256]),
                     fmaxf(dst_lds[t+512], dst_lds[t+768]));
    #pragma unroll
    for (int off = 32; off > 0; off >>= 1) mx = fmaxf(mx, __shfl_down(mx, off));
    if (lane == 0) red_lds[w] = mx;
    __syncthreads();
    const float maxdst = fmaxf(fmaxf(red_lds[0], red_lds[1]),
                               fmaxf(red_lds[2], red_lds[3]));

    const float sv = src_lds[myrow];
    const float s0 = sv + maxdst;
    const float mi = fmaxf(s0, LEAK*s0);

    float16 acc0, acc1;
    #pragma unroll
    for (int i = 0; i < 16; ++i) { acc0[i] = 0.f; acc1[i] = 0.f; }
    float psum = 0.f;

    #pragma unroll
    for (int jtl = 0; jtl < 8; ++jtl) {
        __syncthreads();
        {   // stage BOTH jt-half tiles: threads 0..127 -> buf0, 128..255 -> buf1
            const int buf = t >> 7;
            const int tt  = t & 127;
            const int o = tt >> 1, h16 = tt & 1;
            const uint4* src = (const uint4*)
                (hpt + ((size_t)g*64 + o)*NN + (buf*8 + jtl)*64 + h16*32);
            const uint4 v0 = src[0], v1 = src[1], v2 = src[2], v3 = src[3];
            uint4* dp = (uint4*)&tile[buf*4608 + o*72 + h16*32];
            dp[0] = v0; dp[1] = v1; dp[2] = v2; dp[3] = v3;
        }
        const int jt = jh*8 + jtl;
        const unsigned long long wb = brg[jtl];
        __syncthreads();

        #pragma unroll
        for (int ks = 0; ks < 4; ++ks) {
            const int jb = jt*64 + ks*16 + half*8;
            const float4 d0 = *(const float4*)&dst_lds[jb];
            const float4 d1 = *(const float4*)&dst_lds[jb + 4];
            const unsigned bb = (unsigned)(wb >> (ks*16 + half*8)) & 0xffu;

            union { short8 v; unsigned short u[8]; } af;
            float s, l, p;
            s = sv + d0.x; l = fmaxf(s, LEAK*s); p = (bb & 1u)   ? __expf(l - mi) : 0.f; psum += p; af.u[0] = f2bf_rne(p);
            s = sv + d0.y; l = fmaxf(s, LEAK*s); p = (bb & 2u)   ? __expf(l - mi) : 0.f; psum += p; af.u[1] = f2bf_rne(p);
            s = sv + d0.z; l = fmaxf(s, LEAK*s); p = (bb & 4u)   ? __expf(l - mi) : 0.f; psum += p; af.u[2] = f2bf_rne(p);
            s = sv + d0.w; l = fmaxf(s, LEAK*s); p = (bb & 8u)   ? __expf(l - mi) : 0.f; psum += p; af.u[3] = f2bf_rne(p);
            s = sv + d1.x; l = fmaxf(s, LEAK*s); p = (bb & 16u)  ? __expf(l - mi) : 0.f; psum += p; af.u[4] = f2bf_rne(p);
            s = sv + d1.y; l = fmaxf(s, LEAK*s); p = (bb & 32u)  ? __expf(l - mi) : 0.f; psum += p; af.u[5] = f2bf_rne(p);
            s = sv + d1.z; l = fmaxf(s, LEAK*s); p = (bb & 64u)  ? __expf(l - mi) : 0.f; psum += p; af.u[6] = f2bf_rne(p);
            s = sv + d1.w; l = fmaxf(s, LEAK*s); p = (bb & 128u) ? __expf(l - mi) : 0.f; psum += p; af.u[7] = f2bf_rne(p);

            const short8 b0 = *(const short8*)&tile[jh*4608 + (l31     )*72 + ks*16 + half*8];
            const short8 b1 = *(const short8*)&tile[jh*4608 + (l31 + 32)*72 + ks*16 + half*8];
            acc0 = __builtin_amdgcn_mfma_f32_32x32x16_bf16(af.v, b0, acc0, 0, 0, 0);
            acc1 = __builtin_amdgcn_mfma_f32_32x32x16_bf16(af.v, b1, acc1, 0, 0, 0);
        }
    }

    // combine halves within wave (j%16 split across lane halves)
    psum += __shfl_xor(psum, 32);
    __syncthreads();   // all tile reads done -> safe to overlay comb

    if (jh == 1) {     // odd waves publish partials
        float* cb = comb + (rg*64 + lane)*34;
        #pragma unroll
        for (int i = 0; i < 8; ++i) {
            float2 v0; v0.x = acc0[2*i]; v0.y = acc0[2*i+1];
            float2 v1; v1.x = acc1[2*i]; v1.y = acc1[2*i+1];
            *(float2*)&cb[2*i]      = v0;
            *(float2*)&cb[16 + 2*i] = v1;
        }
        if (lane < 32) ps_buf[rg*32 + l31] = psum;
    }
    __syncthreads();
    if (jh == 0) {     // even waves merge + publish combined row sums
        const float* cb = comb + (rg*64 + lane)*34;
        #pragma unroll
        for (int i = 0; i < 8; ++i) {
            const float2 v0 = *(const float2*)&cb[2*i];
            const float2 v1 = *(const float2*)&cb[16 + 2*i];
            acc0[2*i] += v0.x; acc0[2*i+1] += v0.y;
            acc1[2*i] += v1.x; acc1[2*i+1] += v1.y;
        }
        psum += ps_buf[rg*32 + l31];
        if (lane < 32) ps_buf[rg*32 + l31] = psum;
    }
    __syncthreads();
    if (jh == 0) {
        #pragma unroll
        for (int reg = 0; reg < 16; ++reg) {
            const int r = (reg & 3) + 8*(reg >> 2) + 4*half;
            const float inv = __builtin_amdgcn_rcpf(ps_buf[rg*32 + r]);
            const size_t base = ((size_t)g*NN + i0 + rg*32 + r)*NF;
            out[base + l31]      = acc0[reg] * inv;
            out[base + l31 + 32] = acc1[reg] * inv;
        }
    }
}

// ---------------------------------------------------------------------------
extern "C" void kernel_launch(void* const* d_in, const int* in_sizes, int n_in,
                              void* d_out, int out_size, void* d_ws, size_t ws_size,
                              hipStream_t stream)
{
    const float* h     = (const float*)d_in[0];
    const float* adj   = (const float*)d_in[1];
    const float* w     = (const float*)d_in[2];
    const float* a_src = (const float*)d_in[3];
    const float* a_dst = (const float*)d_in[4];
    float* out = (float*)d_out;

    char* ws = (char*)d_ws;
    // ws: hpt bf16 [64][64][1024] (8,388,608 B) | asrc (262,144) | adst (262,144)
    //     | bits u64 [4][1024][16] (524,288)
    unsigned short* hpt  = (unsigned short*)ws;
    float* asrc          = (float*)(ws + 8388608);
    float* adst          = (float*)(ws + 8388608 + 262144);
    unsigned long long* bits = (unsigned long long*)(ws + 8388608 + 524288);

    k1_hprime<<<dim3(NCOMBO*16), dim3(256), 0, stream>>>(h, w, a_src, a_dst, hpt, asrc, adst);
    k2_bits  <<<dim3(NB*NN*NN/256), dim3(256), 0, stream>>>(adj, bits);
    k3_attn  <<<dim3(1024), dim3(256), 0, stream>>>(hpt, asrc, adst, bits, out);
}

// Round 5
// 138.755 us; speedup vs baseline: 2.1468x; 1.0103x over previous
//
#include <hip/hip_runtime.h>
#include <hip/hip_bf16.h>
#include <math.h>

// Problem constants
#define NB 4
#define NC 4
#define NH 4
#define NN 1024
#define NF 64
#define NCOMBO 64
#define LEAK 0.2f

typedef __attribute__((ext_vector_type(8)))  short  short8;
typedef __attribute__((ext_vector_type(16))) float  float16;

// packed RNE f32x2 -> bf16x2 via v_cvt_pk_bf16_f32
static __device__ __forceinline__ unsigned pk_bf16(float a, float b) {
    union { __hip_bfloat162 h; unsigned u; } cv;
    cv.h = __float22bfloat162_rn(make_float2(a, b));
    return cv.u;
}

// tanh via hardware exp+rcp: 1 - 2/(1+e^{2x}); err ~1e-6, saturates correctly
static __device__ __forceinline__ float fast_tanh(float x) {
    const float e = __expf(2.f * x);
    return 1.f - 2.f * __builtin_amdgcn_rcpf(1.f + e);
}

// ---------------------------------------------------------------------------
// k1: hp = h @ w per combo. LDS-tiled fp32 GEMM, 4x4 acc per thread.
// Writes hpt[g][o][n] bf16 (transposed) + asrc/adst fp32 score vectors.
// ---------------------------------------------------------------------------
__global__ __launch_bounds__(256) void k1_hprime(
    const float* __restrict__ h, const float* __restrict__ w,
    const float* __restrict__ a_src, const float* __restrict__ a_dst,
    unsigned short* __restrict__ hpt, float* __restrict__ asrc,
    float* __restrict__ adst)
{
    __shared__ __align__(16) char ovr[64*65*4];   // hT[f][r] stride 65; later redS/redD
    __shared__ float w_s[NF*NF];                  // w_s[f][o] 16KB
    __shared__ float as_lds[NF], ad_lds[NF];
    float* hT = (float*)ovr;

    const int g    = blockIdx.x >> 4;
    const int tile = blockIdx.x & 15;
    const int b = g >> 4, c = (g >> 2) & 3, hh = g & 3;
    const int t = threadIdx.x;
    const int tr = t >> 4, tc = t & 15;

    const float4* wsrc = (const float4*)(w + ((size_t)(c*NH + hh))*NF*NF);
    #pragma unroll
    for (int i = 0; i < 4; ++i)
        ((float4*)w_s)[t + i*256] = wsrc[t + i*256];
    if (t < NF) {
        as_lds[t] = a_src[(c*NH + hh)*NF + t];
        ad_lds[t] = a_dst[(c*NH + hh)*NF + t];
    }
    const float* hsrc = h + (((size_t)(b*NC + c))*NN + tile*64)*NF;
    #pragma unroll
    for (int i = 0; i < 4; ++i) {
        const int r = (t >> 4) + i*16, f4 = (t & 15)*4;
        const float4 v = *(const float4*)&hsrc[r*NF + f4];
        hT[(f4+0)*65 + r] = v.x; hT[(f4+1)*65 + r] = v.y;
        hT[(f4+2)*65 + r] = v.z; hT[(f4+3)*65 + r] = v.w;
    }
    __syncthreads();

    float acc[4][4] = {{0.f}};
    #pragma unroll 8
    for (int f = 0; f < 64; ++f) {
        const float4 hv = *(const float4*)&hT[f*65 + tr*4];
        const float4 wv = *(const float4*)&w_s[f*64 + tc*4];
        acc[0][0] = fmaf(hv.x, wv.x, acc[0][0]);
        acc[0][1] = fmaf(hv.x, wv.y, acc[0][1]);
        acc[0][2] = fmaf(hv.x, wv.z, acc[0][2]);
        acc[0][3] = fmaf(hv.x, wv.w, acc[0][3]);
        acc[1][0] = fmaf(hv.y, wv.x, acc[1][0]);
        acc[1][1] = fmaf(hv.y, wv.y, acc[1][1]);
        acc[1][2] = fmaf(hv.y, wv.z, acc[1][2]);
        acc[1][3] = fmaf(hv.y, wv.w, acc[1][3]);
        acc[2][0] = fmaf(hv.z, wv.x, acc[2][0]);
        acc[2][1] = fmaf(hv.z, wv.y, acc[2][1]);
        acc[2][2] = fmaf(hv.z, wv.z, acc[2][2]);
        acc[2][3] = fmaf(hv.z, wv.w, acc[2][3]);
        acc[3][0] = fmaf(hv.w, wv.x, acc[3][0]);
        acc[3][1] = fmaf(hv.w, wv.y, acc[3][1]);
        acc[3][2] = fmaf(hv.w, wv.z, acc[3][2]);
        acc[3][3] = fmaf(hv.w, wv.w, acc[3][3]);
    }

    float ps[4] = {0.f,0.f,0.f,0.f}, pd[4] = {0.f,0.f,0.f,0.f};
    #pragma unroll
    for (int r = 0; r < 4; ++r)
        #pragma unroll
        for (int cc = 0; cc < 4; ++cc) {
            const float tt = fast_tanh(acc[r][cc]);
            ps[r] = fmaf(tt, as_lds[tc*4+cc], ps[r]);
            pd[r] = fmaf(tt, ad_lds[tc*4+cc], pd[r]);
        }
    __syncthreads();                     // hT dead -> overlay
    float* redS = (float*)ovr;           // [64][16]
    float* redD = redS + 1024;
    #pragma unroll
    for (int r = 0; r < 4; ++r) {
        redS[(tr*4+r)*16 + tc] = ps[r];
        redD[(tr*4+r)*16 + tc] = pd[r];
    }
    __syncthreads();
    if (t < 64) {
        float4 s0 = *(const float4*)&redS[t*16],     s1 = *(const float4*)&redS[t*16+4];
        float4 s2 = *(const float4*)&redS[t*16+8],   s3 = *(const float4*)&redS[t*16+12];
        asrc[(size_t)g*NN + tile*64 + t] =
            (s0.x+s0.y+s0.z+s0.w) + (s1.x+s1.y+s1.z+s1.w) +
            (s2.x+s2.y+s2.z+s2.w) + (s3.x+s3.y+s3.z+s3.w);
        float4 d0 = *(const float4*)&redD[t*16],     d1 = *(const float4*)&redD[t*16+4];
        float4 d2 = *(const float4*)&redD[t*16+8],   d3 = *(const float4*)&redD[t*16+12];
        adst[(size_t)g*NN + tile*64 + t] =
            (d0.x+d0.y+d0.z+d0.w) + (d1.x+d1.y+d1.z+d1.w) +
            (d2.x+d2.y+d2.z+d2.w) + (d3.x+d3.y+d3.z+d3.w);
    }
    // transposed bf16 hp write (hw packed cvt)
    #pragma unroll
    for (int cc = 0; cc < 4; ++cc) {
        const int o = tc*4 + cc;
        uint2 pk;
        pk.x = pk_bf16(acc[0][cc], acc[1][cc]);
        pk.y = pk_bf16(acc[2][cc], acc[3][cc]);
        *(uint2*)&hpt[((size_t)g*64 + o)*NN + tile*64 + tr*4] = pk;
    }
}

// ---------------------------------------------------------------------------
// k2: bits[b][i][j/64] — bit set where (adj[b,i,j] != 0) || (j == i)
// ---------------------------------------------------------------------------
__global__ __launch_bounds__(256) void k2_bits(
    const float* __restrict__ adj, unsigned long long* __restrict__ bits)
{
    const int idx = blockIdx.x*256 + threadIdx.x;   // over B*N*N = 4M
    const int j  = idx & (NN-1);
    const int i  = (idx >> 10) & (NN-1);
    const int bb = idx >> 20;
    const float av = adj[idx];
    const bool pred = (av != 0.f) || (j == i);
    const unsigned long long m = __ballot(pred);
    if ((j & 63) == 0) bits[((size_t)bb*NN + i)*(NN/64) + (j >> 6)] = m;
}

// ---------------------------------------------------------------------------
// k3: block = one combo g x 64 i-rows, 4 waves. Wave w: rowgroup rg=w>>1
// (rows rg*32..+31), jt-half jh=w&1 (jt in [jh*8, jh*8+8)). Pairs combine
// partial accumulators + row sums through LDS at the end.
//
// Factored softmax (no exp in inner loop):
//   s = sv + d;  p = bit * ( s>=0 ? exp(d)*exp(sv-m) : exp(.2d)*exp(.2sv-m) )
//   s>=0  <=>  exp(d) >= exp(-sv)   (exp monotone)
// m = lrelu(sv + max_j d_j), a valid upper bound of the masked row max
// (lrelu monotone; diag always unmasked -> no underflow of the row).
//
// hp tile staged in MFMA-B-fragment order: frag[ks][sub][half][l31][8 bf16]
// -> every ds_read_b128 is lane-linear (conflict-free).
// ---------------------------------------------------------------------------
__global__ __launch_bounds__(256, 4) void k3_attn(
    const unsigned short* __restrict__ hpt, const float* __restrict__ asrc,
    const float* __restrict__ adst, const unsigned long long* __restrict__ bits,
    float* __restrict__ out)
{
    __shared__ float edP[NN];                        // exp(dst)      4KB
    __shared__ float edN[NN];                        // exp(.2*dst)   4KB
    __shared__ float src_lds[64];
    __shared__ float ps_buf[64];
    __shared__ float red_lds[4];
    __shared__ unsigned long long bits_lds[64*17];   // stride 17 u64, 8.7KB
    // overlay: frag[2][4096] bf16 (16KB) during loop; comb[2][64*34] f32 after
    __shared__ __align__(16) char ovraw[2*64*34*4];  // 17408B
    unsigned short* frag = (unsigned short*)ovraw;
    float* comb = (float*)ovraw;

    const int g  = blockIdx.x & 63;    // same-g blocks -> same XCD (L2 reuse)
    const int it = blockIdx.x >> 6;    // 0..15
    const int b  = g >> 4;
    const int t  = threadIdx.x;
    const int i0 = it*64;
    const int w = t >> 6, lane = t & 63;
    const int l31 = lane & 31, half = lane >> 5;
    const int rg = w >> 1, jh = w & 1;
    const int myrow = rg*32 + l31;

    // prologue: exp tables + unmasked max of dst + src + bits
    float mx = -1e30f;
    #pragma unroll
    for (int q = 0; q < 4; ++q) {
        const float d = adst[(size_t)g*NN + q*256 + t];
        edP[q*256 + t] = __expf(d);
        edN[q*256 + t] = __expf(LEAK*d);
        mx = fmaxf(mx, d);
    }
    if (t < 64) src_lds[t] = asrc[(size_t)g*NN + i0 + t];
    {
        const unsigned long long* bsrc = bits + ((size_t)b*NN + i0)*16;
        #pragma unroll
        for (int q = 0; q < 4; ++q) {
            const int idx = q*256 + t;               // row = idx>>4, col = idx&15
            bits_lds[(idx >> 4)*17 + (idx & 15)] = bsrc[idx];
        }
    }
    #pragma unroll
    for (int off = 32; off > 0; off >>= 1) mx = fmaxf(mx, __shfl_down(mx, off));
    if (lane == 0) red_lds[w] = mx;
    __syncthreads();
    const float maxdst = fmaxf(fmaxf(red_lds[0], red_lds[1]),
                               fmaxf(red_lds[2], red_lds[3]));

    const float sv  = src_lds[myrow];
    const float s0  = sv + maxdst;
    const float mi  = fmaxf(s0, LEAK*s0);
    const float esP = __expf(sv - mi);
    const float esN = __expf(LEAK*sv - mi);
    const float ethr = __expf(-sv);     // edP[j] >= ethr  <=>  sv + dst[j] >= 0

    float16 acc0, acc1;
    #pragma unroll
    for (int i = 0; i < 16; ++i) { acc0[i] = 0.f; acc1[i] = 0.f; }
    float psum = 0.f;

    for (int jtl = 0; jtl < 8; ++jtl) {
        __syncthreads();
        {   // stage both jh tiles in fragment order; threads 0..127 buf0, rest buf1
            const int buf = t >> 7, tt = t & 127;
            const int o = tt >> 1, h16 = tt & 1;
            const int sub = o >> 5, ol = o & 31;
            const uint4* src = (const uint4*)
                (hpt + ((size_t)g*64 + o)*NN + (buf*8 + jtl)*64 + h16*32);
            #pragma unroll
            for (int c = 0; c < 4; ++c) {
                const int ks = h16*2 + (c >> 1), hf = c & 1;
                const uint4 v = src[c];
                *(uint4*)&frag[buf*4096 + ((((ks*2 + sub)*2 + hf)*32) + ol)*8] = v;
            }
        }
        const unsigned long long wb = bits_lds[myrow*17 + jh*8 + jtl];
        __syncthreads();

        #pragma unroll
        for (int ks = 0; ks < 4; ++ks) {
            const int jb = (jh*8 + jtl)*64 + ks*16 + half*8;  // wave-uniform
            const float4 P0 = *(const float4*)&edP[jb];
            const float4 P1 = *(const float4*)&edP[jb + 4];
            const float4 N0 = *(const float4*)&edN[jb];
            const float4 N1 = *(const float4*)&edN[jb + 4];
            const unsigned bb = (unsigned)(wb >> (ks*16 + half*8)) & 0xffu;

            float p0, p1, p2, p3, p4, p5, p6, p7;
            p0 = (P0.x >= ethr) ? P0.x*esP : N0.x*esN; p0 = (bb & 1u)   ? p0 : 0.f;
            p1 = (P0.y >= ethr) ? P0.y*esP : N0.y*esN; p1 = (bb & 2u)   ? p1 : 0.f;
            p2 = (P0.z >= ethr) ? P0.z*esP : N0.z*esN; p2 = (bb & 4u)   ? p2 : 0.f;
            p3 = (P0.w >= ethr) ? P0.w*esP : N0.w*esN; p3 = (bb & 8u)   ? p3 : 0.f;
            p4 = (P1.x >= ethr) ? P1.x*esP : N1.x*esN; p4 = (bb & 16u)  ? p4 : 0.f;
            p5 = (P1.y >= ethr) ? P1.y*esP : N1.y*esN; p5 = (bb & 32u)  ? p5 : 0.f;
            p6 = (P1.z >= ethr) ? P1.z*esP : N1.z*esN; p6 = (bb & 64u)  ? p6 : 0.f;
            p7 = (P1.w >= ethr) ? P1.w*esP : N1.w*esN; p7 = (bb & 128u) ? p7 : 0.f;
            psum += ((p0 + p1) + (p2 + p3)) + ((p4 + p5) + (p6 + p7));

            union { short8 v; unsigned u[4]; } af;
            af.u[0] = pk_bf16(p0, p1);
            af.u[1] = pk_bf16(p2, p3);
            af.u[2] = pk_bf16(p4, p5);
            af.u[3] = pk_bf16(p6, p7);

            const short8 b0 = *(const short8*)
                &frag[jh*4096 + (((ks*2 + 0)*2 + half)*32 + l31)*8];
            const short8 b1 = *(const short8*)
                &frag[jh*4096 + (((ks*2 + 1)*2 + half)*32 + l31)*8];
            acc0 = __builtin_amdgcn_mfma_f32_32x32x16_bf16(af.v, b0, acc0, 0, 0, 0);
            acc1 = __builtin_amdgcn_mfma_f32_32x32x16_bf16(af.v, b1, acc1, 0, 0, 0);
        }
    }

    // combine halves within wave (j%16 split across lane halves)
    psum += __shfl_xor(psum, 32);
    __syncthreads();   // frag reads done -> safe to overlay comb

    if (jh == 1) {     // odd waves publish partials
        float* cb = comb + (rg*64 + lane)*34;
        #pragma unroll
        for (int i = 0; i < 8; ++i) {
            float2 v0; v0.x = acc0[2*i]; v0.y = acc0[2*i+1];
            float2 v1; v1.x = acc1[2*i]; v1.y = acc1[2*i+1];
            *(float2*)&cb[2*i]      = v0;
            *(float2*)&cb[16 + 2*i] = v1;
        }
        if (lane < 32) ps_buf[rg*32 + l31] = psum;
    }
    __syncthreads();
    if (jh == 0) {     // even waves merge + publish combined row sums
        const float* cb = comb + (rg*64 + lane)*34;
        #pragma unroll
        for (int i = 0; i < 8; ++i) {
            const float2 v0 = *(const float2*)&cb[2*i];
            const float2 v1 = *(const float2*)&cb[16 + 2*i];
            acc0[2*i] += v0.x; acc0[2*i+1] += v0.y;
            acc1[2*i] += v1.x; acc1[2*i+1] += v1.y;
        }
        psum += ps_buf[rg*32 + l31];
        if (lane < 32) ps_buf[rg*32 + l31] = psum;
    }
    __syncthreads();
    if (jh == 0) {
        #pragma unroll
        for (int reg = 0; reg < 16; ++reg) {
            const int r = (reg & 3) + 8*(reg >> 2) + 4*half;
            const float inv = __builtin_amdgcn_rcpf(ps_buf[rg*32 + r]);
            const size_t base = ((size_t)g*NN + i0 + rg*32 + r)*NF;
            out[base + l31]      = acc0[reg] * inv;
            out[base + l31 + 32] = acc1[reg] * inv;
        }
    }
}

// ---------------------------------------------------------------------------
extern "C" void kernel_launch(void* const* d_in, const int* in_sizes, int n_in,
                              void* d_out, int out_size, void* d_ws, size_t ws_size,
                              hipStream_t stream)
{
    const float* h     = (const float*)d_in[0];
    const float* adj   = (const float*)d_in[1];
    const float* w     = (const float*)d_in[2];
    const float* a_src = (const float*)d_in[3];
    const float* a_dst = (const float*)d_in[4];
    float* out = (float*)d_out;

    char* ws = (char*)d_ws;
    // ws: hpt bf16 [64][64][1024] (8,388,608 B) | asrc (262,144) | adst (262,144)
    //     | bits u64 [4][1024][16] (524,288)
    unsigned short* hpt  = (unsigned short*)ws;
    float* asrc          = (float*)(ws + 8388608);
    float* adst          = (float*)(ws + 8388608 + 262144);
    unsigned long long* bits = (unsigned long long*)(ws + 8388608 + 524288);

    k1_hprime<<<dim3(NCOMBO*16), dim3(256), 0, stream>>>(h, w, a_src, a_dst, hpt, asrc, adst);
    k2_bits  <<<dim3(NB*NN*NN/256), dim3(256), 0, stream>>>(adj, bits);
    k3_attn  <<<dim3(1024), dim3(256), 0, stream>>>(hpt, asrc, adst, bits, out);
}

// Round 6
// 133.299 us; speedup vs baseline: 2.2347x; 1.0409x over previous
//
#include <hip/hip_runtime.h>
#include <hip/hip_bf16.h>
#include <math.h>

// Problem constants
#define NB 4
#define NC 4
#define NH 4
#define NN 1024
#define NF 64
#define NCOMBO 64
#define LEAK 0.2f

typedef __attribute__((ext_vector_type(8)))  short  short8;
typedef __attribute__((ext_vector_type(16))) float  float16;

// packed RNE f32x2 -> bf16x2 via v_cvt_pk_bf16_f32
static __device__ __forceinline__ unsigned pk_bf16(float a, float b) {
    union { __hip_bfloat162 h; unsigned u; } cv;
    cv.h = __float22bfloat162_rn(make_float2(a, b));
    return cv.u;
}

// tanh via hardware exp+rcp: 1 - 2/(1+e^{2x}); err ~1e-6, saturates correctly
static __device__ __forceinline__ float fast_tanh(float x) {
    const float e = __expf(2.f * x);
    return 1.f - 2.f * __builtin_amdgcn_rcpf(1.f + e);
}

// async global->LDS, 16B per lane; ldst must be wave-uniform (dst = base+lane*16)
static __device__ __forceinline__ void async_cp16(const void* gsrc, void* ldst) {
    __builtin_amdgcn_global_load_lds(
        (const __attribute__((address_space(1))) unsigned int*)gsrc,
        (__attribute__((address_space(3))) unsigned int*)ldst, 16, 0, 0);
}

// ---------------------------------------------------------------------------
// k1: hp = h @ w per combo. LDS-tiled fp32 GEMM, 4x4 acc per thread.
// Writes hpt in MFMA-B-FRAGMENT order (per g, per 64-j tile, 4096 bf16):
//   pos(o,j) = (((j>>4)*2 + (o>>5))*2 + ((j>>3)&1))*32 + (o&31))*8 + (j&7)
// so k3 can stage tiles with a verbatim contiguous copy (global_load_lds).
// Also writes asrc/adst fp32 score vectors.
// ---------------------------------------------------------------------------
__global__ __launch_bounds__(256) void k1_hprime(
    const float* __restrict__ h, const float* __restrict__ w,
    const float* __restrict__ a_src, const float* __restrict__ a_dst,
    unsigned short* __restrict__ hpt, float* __restrict__ asrc,
    float* __restrict__ adst)
{
    __shared__ __align__(16) char ovr[64*65*4];   // hT[f][r] stride 65; later redS/redD
    __shared__ float w_s[NF*NF];                  // w_s[f][o] 16KB
    __shared__ float as_lds[NF], ad_lds[NF];
    float* hT = (float*)ovr;

    const int g    = blockIdx.x >> 4;
    const int tile = blockIdx.x & 15;
    const int b = g >> 4, c = (g >> 2) & 3, hh = g & 3;
    const int t = threadIdx.x;
    const int tr = t >> 4, tc = t & 15;

    const float4* wsrc = (const float4*)(w + ((size_t)(c*NH + hh))*NF*NF);
    #pragma unroll
    for (int i = 0; i < 4; ++i)
        ((float4*)w_s)[t + i*256] = wsrc[t + i*256];
    if (t < NF) {
        as_lds[t] = a_src[(c*NH + hh)*NF + t];
        ad_lds[t] = a_dst[(c*NH + hh)*NF + t];
    }
    const float* hsrc = h + (((size_t)(b*NC + c))*NN + tile*64)*NF;
    #pragma unroll
    for (int i = 0; i < 4; ++i) {
        const int r = (t >> 4) + i*16, f4 = (t & 15)*4;
        const float4 v = *(const float4*)&hsrc[r*NF + f4];
        hT[(f4+0)*65 + r] = v.x; hT[(f4+1)*65 + r] = v.y;
        hT[(f4+2)*65 + r] = v.z; hT[(f4+3)*65 + r] = v.w;
    }
    __syncthreads();

    float acc[4][4] = {{0.f}};
    #pragma unroll 8
    for (int f = 0; f < 64; ++f) {
        const float4 hv = *(const float4*)&hT[f*65 + tr*4];
        const float4 wv = *(const float4*)&w_s[f*64 + tc*4];
        acc[0][0] = fmaf(hv.x, wv.x, acc[0][0]);
        acc[0][1] = fmaf(hv.x, wv.y, acc[0][1]);
        acc[0][2] = fmaf(hv.x, wv.z, acc[0][2]);
        acc[0][3] = fmaf(hv.x, wv.w, acc[0][3]);
        acc[1][0] = fmaf(hv.y, wv.x, acc[1][0]);
        acc[1][1] = fmaf(hv.y, wv.y, acc[1][1]);
        acc[1][2] = fmaf(hv.y, wv.z, acc[1][2]);
        acc[1][3] = fmaf(hv.y, wv.w, acc[1][3]);
        acc[2][0] = fmaf(hv.z, wv.x, acc[2][0]);
        acc[2][1] = fmaf(hv.z, wv.y, acc[2][1]);
        acc[2][2] = fmaf(hv.z, wv.z, acc[2][2]);
        acc[2][3] = fmaf(hv.z, wv.w, acc[2][3]);
        acc[3][0] = fmaf(hv.w, wv.x, acc[3][0]);
        acc[3][1] = fmaf(hv.w, wv.y, acc[3][1]);
        acc[3][2] = fmaf(hv.w, wv.z, acc[3][2]);
        acc[3][3] = fmaf(hv.w, wv.w, acc[3][3]);
    }

    float ps[4] = {0.f,0.f,0.f,0.f}, pd[4] = {0.f,0.f,0.f,0.f};
    #pragma unroll
    for (int r = 0; r < 4; ++r)
        #pragma unroll
        for (int cc = 0; cc < 4; ++cc) {
            const float tt = fast_tanh(acc[r][cc]);
            ps[r] = fmaf(tt, as_lds[tc*4+cc], ps[r]);
            pd[r] = fmaf(tt, ad_lds[tc*4+cc], pd[r]);
        }
    __syncthreads();                     // hT dead -> overlay
    float* redS = (float*)ovr;           // [64][16]
    float* redD = redS + 1024;
    #pragma unroll
    for (int r = 0; r < 4; ++r) {
        redS[(tr*4+r)*16 + tc] = ps[r];
        redD[(tr*4+r)*16 + tc] = pd[r];
    }
    __syncthreads();
    if (t < 64) {
        float4 s0 = *(const float4*)&redS[t*16],     s1 = *(const float4*)&redS[t*16+4];
        float4 s2 = *(const float4*)&redS[t*16+8],   s3 = *(const float4*)&redS[t*16+12];
        asrc[(size_t)g*NN + tile*64 + t] =
            (s0.x+s0.y+s0.z+s0.w) + (s1.x+s1.y+s1.z+s1.w) +
            (s2.x+s2.y+s2.z+s2.w) + (s3.x+s3.y+s3.z+s3.w);
        float4 d0 = *(const float4*)&redD[t*16],     d1 = *(const float4*)&redD[t*16+4];
        float4 d2 = *(const float4*)&redD[t*16+8],   d3 = *(const float4*)&redD[t*16+12];
        adst[(size_t)g*NN + tile*64 + t] =
            (d0.x+d0.y+d0.z+d0.w) + (d1.x+d1.y+d1.z+d1.w) +
            (d2.x+d2.y+d2.z+d2.w) + (d3.x+d3.y+d3.z+d3.w);
    }
    // fragment-order bf16 hp write: j = tr*4 + r, o = tc*4 + cc
    #pragma unroll
    for (int cc = 0; cc < 4; ++cc) {
        const int o = tc*4 + cc;
        const int pos = (((((tr>>2)*2 + (o>>5))*2 + ((tr>>1)&1))*32 + (o&31))*8)
                        + (tr&1)*4;
        uint2 pk;
        pk.x = pk_bf16(acc[0][cc], acc[1][cc]);
        pk.y = pk_bf16(acc[2][cc], acc[3][cc]);
        *(uint2*)&hpt[((size_t)g*16 + tile)*4096 + pos] = pk;
    }
}

// ---------------------------------------------------------------------------
// k2: bits[b][i][j/64] — bit set where (adj[b,i,j] != 0) || (j == i)
// ---------------------------------------------------------------------------
__global__ __launch_bounds__(256) void k2_bits(
    const float* __restrict__ adj, unsigned long long* __restrict__ bits)
{
    const int idx = blockIdx.x*256 + threadIdx.x;   // over B*N*N = 4M
    const int j  = idx & (NN-1);
    const int i  = (idx >> 10) & (NN-1);
    const int bb = idx >> 20;
    const float av = adj[idx];
    const bool pred = (av != 0.f) || (j == i);
    const unsigned long long m = __ballot(pred);
    if ((j & 63) == 0) bits[((size_t)bb*NN + i)*(NN/64) + (j >> 6)] = m;
}

// ---------------------------------------------------------------------------
// k3: block = one combo g x 64 i-rows, 4 waves. Wave w = (rg = w>>1, jh = w&1):
// rows rg*32..+31, ks in {2jh, 2jh+1} of each 64-j tile. All 16 j-tiles
// iterate with double-buffered async staging (global_load_lds width=16,
// verbatim copy — hpt is pre-swizzled to fragment order by k1).
//
// P-gen (branchless, no exp in loop):  exp(lrelu(s)) = max(exp(s), exp(.2s))
//   p = bit * max(edP[j]*esP, edN[j]*esN),  esP = exp(sv-mi), esN = exp(.2sv-mi)
// mi = lrelu(sv + max_j dst_j), valid upper bound (lrelu monotone, diag unmasked).
// ---------------------------------------------------------------------------
__global__ __launch_bounds__(256, 4) void k3_attn(
    const unsigned short* __restrict__ hpt, const float* __restrict__ asrc,
    const float* __restrict__ adst, const unsigned long long* __restrict__ bits,
    float* __restrict__ out)
{
    __shared__ float edP[NN];                        // exp(dst)      4KB
    __shared__ float edN[NN];                        // exp(.2*dst)   4KB
    __shared__ float src_lds[64];
    __shared__ float ps_buf[64];
    __shared__ float red_lds[4];
    __shared__ unsigned long long bits_lds[64*17];   // stride 17 u64, 8.7KB
    // overlay: frag[2][8192B] during loop; comb[2][64*34] f32 (17408B) after
    __shared__ __align__(16) char ovraw[17408];
    unsigned short* fragB = (unsigned short*)ovraw;
    float* comb = (float*)ovraw;

    const int g  = blockIdx.x & 63;    // same-g blocks 64 apart -> same XCD (L2 reuse)
    const int it = blockIdx.x >> 6;    // 0..15
    const int b  = g >> 4;
    const int t  = threadIdx.x;
    const int i0 = it*64;
    const int w = t >> 6, lane = t & 63;
    const int l31 = lane & 31, half = lane >> 5;
    const int rg = w >> 1, jh = w & 1;
    const int myrow = rg*32 + l31;

    // issue async stage of tile jt=0 into buffer 0 (2 chunks of 1KB per wave)
    {
        const char* gs = (const char*)hpt + ((size_t)g*16 + 0)*8192 + w*2048 + lane*16;
        char* ls = ovraw + w*2048;
        async_cp16(gs, ls);
        async_cp16(gs + 1024, ls + 1024);
    }

    // prologue: exp tables + unmasked max of dst + src + bits
    float mx = -1e30f;
    #pragma unroll
    for (int q = 0; q < 4; ++q) {
        const float d = adst[(size_t)g*NN + q*256 + t];
        edP[q*256 + t] = __expf(d);
        edN[q*256 + t] = __expf(LEAK*d);
        mx = fmaxf(mx, d);
    }
    if (t < 64) src_lds[t] = asrc[(size_t)g*NN + i0 + t];
    {
        const unsigned long long* bsrc = bits + ((size_t)b*NN + i0)*16;
        #pragma unroll
        for (int q = 0; q < 4; ++q) {
            const int idx = q*256 + t;               // row = idx>>4, col = idx&15
            bits_lds[(idx >> 4)*17 + (idx & 15)] = bsrc[idx];
        }
    }
    #pragma unroll
    for (int off = 32; off > 0; off >>= 1) mx = fmaxf(mx, __shfl_down(mx, off));
    if (lane == 0) red_lds[w] = mx;
    __syncthreads();
    const float maxdst = fmaxf(fmaxf(red_lds[0], red_lds[1]),
                               fmaxf(red_lds[2], red_lds[3]));

    const float sv  = src_lds[myrow];
    const float s0  = sv + maxdst;
    const float mi  = fmaxf(s0, LEAK*s0);
    const float esP = __expf(sv - mi);
    const float esN = __expf(LEAK*sv - mi);

    float16 acc0, acc1;
    #pragma unroll
    for (int i = 0; i < 16; ++i) { acc0[i] = 0.f; acc1[i] = 0.f; }
    float psum = 0.f;

    for (int jt = 0; jt < 16; ++jt) {
        __syncthreads();   // drains vmcnt -> tile jt landed; prev reads of other buf done
        const int fb = jt & 1;
        if (jt < 15) {     // issue next tile into the other buffer
            const char* gs = (const char*)hpt + ((size_t)g*16 + jt + 1)*8192
                             + w*2048 + lane*16;
            char* ls = ovraw + (fb ^ 1)*8192 + w*2048;
            async_cp16(gs, ls);
            async_cp16(gs + 1024, ls + 1024);
        }
        const unsigned long long wb = bits_lds[myrow*17 + jt];

        #pragma unroll
        for (int kk = 0; kk < 2; ++kk) {
            const int ks = jh*2 + kk;
            const int jb = jt*64 + ks*16 + half*8;   // wave-uniform base
            const float4 P0 = *(const float4*)&edP[jb];
            const float4 P1 = *(const float4*)&edP[jb + 4];
            const float4 N0 = *(const float4*)&edN[jb];
            const float4 N1 = *(const float4*)&edN[jb + 4];
            const unsigned bb = (unsigned)(wb >> (ks*16 + half*8)) & 0xffu;

            float p0, p1, p2, p3, p4, p5, p6, p7;
            p0 = fmaxf(P0.x*esP, N0.x*esN); p0 = (bb & 1u)   ? p0 : 0.f;
            p1 = fmaxf(P0.y*esP, N0.y*esN); p1 = (bb & 2u)   ? p1 : 0.f;
            p2 = fmaxf(P0.z*esP, N0.z*esN); p2 = (bb & 4u)   ? p2 : 0.f;
            p3 = fmaxf(P0.w*esP, N0.w*esN); p3 = (bb & 8u)   ? p3 : 0.f;
            p4 = fmaxf(P1.x*esP, N1.x*esN); p4 = (bb & 16u)  ? p4 : 0.f;
            p5 = fmaxf(P1.y*esP, N1.y*esN); p5 = (bb & 32u)  ? p5 : 0.f;
            p6 = fmaxf(P1.z*esP, N1.z*esN); p6 = (bb & 64u)  ? p6 : 0.f;
            p7 = fmaxf(P1.w*esP, N1.w*esN); p7 = (bb & 128u) ? p7 : 0.f;
            psum += ((p0 + p1) + (p2 + p3)) + ((p4 + p5) + (p6 + p7));

            union { short8 v; unsigned u[4]; } af;
            af.u[0] = pk_bf16(p0, p1);
            af.u[1] = pk_bf16(p2, p3);
            af.u[2] = pk_bf16(p4, p5);
            af.u[3] = pk_bf16(p6, p7);

            const short8 b0 = *(const short8*)
                &fragB[fb*4096 + (((ks*2 + 0)*2 + half)*32 + l31)*8];
            const short8 b1 = *(const short8*)
                &fragB[fb*4096 + (((ks*2 + 1)*2 + half)*32 + l31)*8];
            acc0 = __builtin_amdgcn_mfma_f32_32x32x16_bf16(af.v, b0, acc0, 0, 0, 0);
            acc1 = __builtin_amdgcn_mfma_f32_32x32x16_bf16(af.v, b1, acc1, 0, 0, 0);
        }
    }

    // combine halves within wave (k-halves of same row across lane halves)
    psum += __shfl_xor(psum, 32);
    __syncthreads();   // frag reads done -> safe to overlay comb

    if (jh == 1) {     // odd waves (ks 2,3) publish partials
        float* cb = comb + (rg*64 + lane)*34;
        #pragma unroll
        for (int i = 0; i < 8; ++i) {
            float2 v0; v0.x = acc0[2*i]; v0.y = acc0[2*i+1];
            float2 v1; v1.x = acc1[2*i]; v1.y = acc1[2*i+1];
            *(float2*)&cb[2*i]      = v0;
            *(float2*)&cb[16 + 2*i] = v1;
        }
        if (lane < 32) ps_buf[rg*32 + l31] = psum;
    }
    __syncthreads();
    if (jh == 0) {     // even waves merge + publish combined row sums
        const float* cb = comb + (rg*64 + lane)*34;
        #pragma unroll
        for (int i = 0; i < 8; ++i) {
            const float2 v0 = *(const float2*)&cb[2*i];
            const float2 v1 = *(const float2*)&cb[16 + 2*i];
            acc0[2*i] += v0.x; acc0[2*i+1] += v0.y;
            acc1[2*i] += v1.x; acc1[2*i+1] += v1.y;
        }
        psum += ps_buf[rg*32 + l31];
        if (lane < 32) ps_buf[rg*32 + l31] = psum;
    }
    __syncthreads();
    if (jh == 0) {
        #pragma unroll
        for (int reg = 0; reg < 16; ++reg) {
            const int r = (reg & 3) + 8*(reg >> 2) + 4*half;
            const float inv = __builtin_amdgcn_rcpf(ps_buf[rg*32 + r]);
            const size_t base = ((size_t)g*NN + i0 + rg*32 + r)*NF;
            out[base + l31]      = acc0[reg] * inv;
            out[base + l31 + 32] = acc1[reg] * inv;
        }
    }
}

// ---------------------------------------------------------------------------
extern "C" void kernel_launch(void* const* d_in, const int* in_sizes, int n_in,
                              void* d_out, int out_size, void* d_ws, size_t ws_size,
                              hipStream_t stream)
{
    const float* h     = (const float*)d_in[0];
    const float* adj   = (const float*)d_in[1];
    const float* w     = (const float*)d_in[2];
    const float* a_src = (const float*)d_in[3];
    const float* a_dst = (const float*)d_in[4];
    float* out = (float*)d_out;

    char* ws = (char*)d_ws;
    // ws: hpt bf16 [64][16][4096] fragment-order (8,388,608 B) | asrc (262,144)
    //     | adst (262,144) | bits u64 [4][1024][16] (524,288)
    unsigned short* hpt  = (unsigned short*)ws;
    float* asrc          = (float*)(ws + 8388608);
    float* adst          = (float*)(ws + 8388608 + 262144);
    unsigned long long* bits = (unsigned long long*)(ws + 8388608 + 524288);

    k1_hprime<<<dim3(NCOMBO*16), dim3(256), 0, stream>>>(h, w, a_src, a_dst, hpt, asrc, adst);
    k2_bits  <<<dim3(NB*NN*NN/256), dim3(256), 0, stream>>>(adj, bits);
    k3_attn  <<<dim3(1024), dim3(256), 0, stream>>>(hpt, asrc, adst, bits, out);
}